// Round 1
// baseline (962.726 us; speedup 1.0000x reference)
//
#include <hip/hip_runtime.h>
#include <math.h>

__device__ __forceinline__ float lrelu(float v){ return v >= 0.f ? v : 0.2f * v; }

// ---------------- CSR build ----------------
__global__ void countK(const int* __restrict__ dstA, int E, int ET, int* __restrict__ deg){
  int e = blockIdx.x * blockDim.x + threadIdx.x;
  if (e >= ET) return;
  int d = (e < E) ? dstA[e] : (e - E);
  atomicAdd(&deg[d], 1);
}

__global__ void scanA(const int* __restrict__ deg, int* __restrict__ excl,
                      int* __restrict__ part, int n){
  __shared__ int s[256];
  int t = threadIdx.x;
  int i = blockIdx.x * 256 + t;
  int v = (i < n) ? deg[i] : 0;
  s[t] = v;
  __syncthreads();
  for (int o = 1; o < 256; o <<= 1){
    int tv = (t >= o) ? s[t - o] : 0;
    __syncthreads();
    s[t] += tv;
    __syncthreads();
  }
  if (i < n) excl[i] = s[t] - v;
  if (t == 255) part[blockIdx.x] = s[t];
}

__global__ void scanB(int* __restrict__ part, int nb){
  __shared__ int s[256];
  int t = threadIdx.x;
  int v = (t < nb) ? part[t] : 0;
  s[t] = v;
  __syncthreads();
  for (int o = 1; o < 256; o <<= 1){
    int tv = (t >= o) ? s[t - o] : 0;
    __syncthreads();
    s[t] += tv;
    __syncthreads();
  }
  if (t < nb) part[t] = s[t] - v;
}

__global__ void scanC(int* __restrict__ off, const int* __restrict__ part, int n, int ET){
  int i = blockIdx.x * 256 + threadIdx.x;
  if (i < n) off[i] += part[blockIdx.x];
  if (i == 0) off[n] = ET;
}

__global__ void scatterK(const int* __restrict__ srcA, const int* __restrict__ dstA, int E, int ET,
                         const int* __restrict__ off, int* __restrict__ cur, int* __restrict__ csrc){
  int e = blockIdx.x * blockDim.x + threadIdx.x;
  if (e >= ET) return;
  int s, d;
  if (e < E){ s = srcA[e]; d = dstA[e]; } else { s = e - E; d = s; }
  int p = off[d] + atomicAdd(&cur[d], 1);
  csrc[p] = s;
}

// ---------------- Layer 1: h1 = x@W1 fused with a_src/a_dst ----------------
__global__ __launch_bounds__(256) void gemm1(const float* __restrict__ x, const float* __restrict__ W1,
    const float* __restrict__ attS, const float* __restrict__ attD,
    float* __restrict__ h1, float* __restrict__ a1s, float* __restrict__ a1d, int nN){
  __shared__ float Ws[128][64];          // W1 columns [64*half, 64*half+64)
  int t = threadIdx.x;
  int half = blockIdx.y;                 // channel half == head (HID=64)
  for (int idx = t; idx < 128 * 64; idx += 256){
    int k = idx >> 6, c = idx & 63;
    Ws[k][c] = W1[k * 128 + half * 64 + c];
  }
  __syncthreads();
  int cl = t & 63;       // channel within head
  int slot = t >> 6;     // wave id: each wave = one node at a time, all 64 ch of this head
  float aS = attS[half * 64 + cl];
  float aD = attD[half * 64 + cl];
  int node0 = blockIdx.x * 16;
  for (int i = 0; i < 4; ++i){
    int n = node0 + slot * 4 + i;
    if (n >= nN) break;
    const float4* xr = reinterpret_cast<const float4*>(x + (size_t)n * 128);
    float acc = 0.f;
    #pragma unroll
    for (int k4 = 0; k4 < 32; ++k4){
      float4 xv = xr[k4];                       // wave-uniform broadcast
      acc = fmaf(xv.x, Ws[4 * k4 + 0][cl], acc);
      acc = fmaf(xv.y, Ws[4 * k4 + 1][cl], acc);
      acc = fmaf(xv.z, Ws[4 * k4 + 2][cl], acc);
      acc = fmaf(xv.w, Ws[4 * k4 + 3][cl], acc);
    }
    h1[(size_t)n * 128 + half * 64 + cl] = acc;
    float ps = acc * aS, pd = acc * aD;
    for (int o = 32; o > 0; o >>= 1){
      ps += __shfl_down(ps, o);
      pd += __shfl_down(pd, o);
    }
    if (cl == 0){
      a1s[n * 2 + half] = ps;
      a1d[n * 2 + half] = pd;
    }
  }
}

// ---------------- Layer 1 attention aggregation (per dst node) ----------------
__global__ __launch_bounds__(128) void agg1(const int* __restrict__ off, const int* __restrict__ csrc,
    const float* __restrict__ a1s, const float* __restrict__ a1d,
    const float* __restrict__ h1, float* __restrict__ elogw,
    const float* __restrict__ b1, float* __restrict__ out1){
  __shared__ float sred[2][2];
  int n = blockIdx.x, t = threadIdx.x;
  int start = off[n], end = off[n + 1];
  float ad0 = a1d[2 * n], ad1 = a1d[2 * n + 1];
  // pass 1: logits + max
  float lm0 = -INFINITY, lm1 = -INFINITY;
  for (int p = start + t; p < end; p += 128){
    int s = csrc[p];
    float l0 = lrelu(a1s[2 * s] + ad0);
    float l1 = lrelu(a1s[2 * s + 1] + ad1);
    elogw[2 * p] = l0; elogw[2 * p + 1] = l1;
    lm0 = fmaxf(lm0, l0); lm1 = fmaxf(lm1, l1);
  }
  for (int o = 32; o > 0; o >>= 1){
    lm0 = fmaxf(lm0, __shfl_down(lm0, o));
    lm1 = fmaxf(lm1, __shfl_down(lm1, o));
  }
  int wid = t >> 6, lane = t & 63;
  if (lane == 0){ sred[wid][0] = lm0; sred[wid][1] = lm1; }
  __syncthreads();
  float m0 = fmaxf(sred[0][0], sred[1][0]);
  float m1 = fmaxf(sred[0][1], sred[1][1]);
  __syncthreads();
  // pass 2: exp + sum
  float ls0 = 0.f, ls1 = 0.f;
  for (int p = start + t; p < end; p += 128){
    float e0 = expf(elogw[2 * p] - m0);
    float e1 = expf(elogw[2 * p + 1] - m1);
    elogw[2 * p] = e0; elogw[2 * p + 1] = e1;
    ls0 += e0; ls1 += e1;
  }
  for (int o = 32; o > 0; o >>= 1){
    ls0 += __shfl_down(ls0, o);
    ls1 += __shfl_down(ls1, o);
  }
  if (lane == 0){ sred[wid][0] = ls0; sred[wid][1] = ls1; }
  __syncthreads();
  float d0 = sred[0][0] + sred[1][0];
  float d1 = sred[0][1] + sred[1][1];
  // pass 3: weighted gather, thread t = channel
  int c = t, h = t >> 6;
  float inv = 1.f / (h ? d1 : d0);
  float bc = b1[c];
  float acc = 0.f;
  for (int p = start; p < end; ++p){
    int s = csrc[p];                               // broadcast
    acc = fmaf(elogw[2 * p + h], h1[(size_t)s * 128 + c], acc);  // coalesced 512B row
  }
  out1[(size_t)n * 128 + c] = fmaxf(fmaf(acc, inv, bc), 0.f);    // + bias, ReLU fused
}

// ---------------- Layer 2: h2 = relu(out1)@W2 fused with a_src2/a_dst2 ----------------
__global__ __launch_bounds__(256) void gemm2(const float* __restrict__ out1, const float* __restrict__ W2,
    const float* __restrict__ attS2, const float* __restrict__ attD2,
    float* __restrict__ h2, float* __restrict__ a2s, float* __restrict__ a2d, int nN){
  __shared__ float Ws[128][8];
  int t = threadIdx.x;
  for (int idx = t; idx < 1024; idx += 256) Ws[idx >> 3][idx & 7] = W2[idx];
  __syncthreads();
  int c = t & 7, nl = t >> 3;
  int n = blockIdx.x * 32 + nl;
  if (n >= nN) return;
  const float4* xr = reinterpret_cast<const float4*>(out1 + (size_t)n * 128);
  float acc = 0.f;
  #pragma unroll
  for (int k4 = 0; k4 < 32; ++k4){
    float4 xv = xr[k4];
    acc = fmaf(xv.x, Ws[4 * k4 + 0][c], acc);
    acc = fmaf(xv.y, Ws[4 * k4 + 1][c], acc);
    acc = fmaf(xv.z, Ws[4 * k4 + 2][c], acc);
    acc = fmaf(xv.w, Ws[4 * k4 + 3][c], acc);
  }
  h2[(size_t)n * 8 + c] = acc;
  float ps = acc * attS2[c], pd = acc * attD2[c];
  ps += __shfl_xor(ps, 1); ps += __shfl_xor(ps, 2); ps += __shfl_xor(ps, 4);
  pd += __shfl_xor(pd, 1); pd += __shfl_xor(pd, 2); pd += __shfl_xor(pd, 4);
  if (c == 0){ a2s[n] = ps; a2d[n] = pd; }
}

// ---------------- Layer 2 attention aggregation (one wave per node) ----------------
__global__ __launch_bounds__(64) void agg2(const int* __restrict__ off, const int* __restrict__ csrc,
    const float* __restrict__ a2s, const float* __restrict__ a2d,
    const float* __restrict__ h2, float* __restrict__ elogw,
    const float* __restrict__ b2, float* __restrict__ out2){
  int n = blockIdx.x, t = threadIdx.x;
  int start = off[n], end = off[n + 1];
  float ad = a2d[n];
  float lm = -INFINITY;
  for (int p = start + t; p < end; p += 64){
    float l = lrelu(a2s[csrc[p]] + ad);
    elogw[p] = l;
    lm = fmaxf(lm, l);
  }
  for (int o = 32; o > 0; o >>= 1) lm = fmaxf(lm, __shfl_down(lm, o));
  lm = __shfl(lm, 0);
  float ls = 0.f;
  for (int p = start + t; p < end; p += 64){
    float e = expf(elogw[p] - lm);
    elogw[p] = e;
    ls += e;
  }
  for (int o = 32; o > 0; o >>= 1) ls += __shfl_down(ls, o);
  float dv = __shfl(ls, 0);
  __syncthreads();   // make other lanes' elogw writes visible
  int c = t & 7, sub = t >> 3;
  float acc = 0.f;
  for (int p = start + sub; p < end; p += 8){
    acc = fmaf(elogw[p], h2[(size_t)csrc[p] * 8 + c], acc);
  }
  acc += __shfl_xor(acc, 8);
  acc += __shfl_xor(acc, 16);
  acc += __shfl_xor(acc, 32);
  if (t < 8) out2[(size_t)n * 8 + t] = fmaxf(acc / dv + b2[t], 0.f);
}

// ---------------- pooling + FC ----------------
__global__ void poolK(const float* __restrict__ out2, const int* __restrict__ batch,
                      float* __restrict__ pooled, float* __restrict__ cnt, int nN){
  int i = blockIdx.x * blockDim.x + threadIdx.x;
  if (i >= nN) return;
  int g = batch[i];
  atomicAdd(&cnt[g], 1.0f);
  #pragma unroll
  for (int c = 0; c < 8; ++c) atomicAdd(&pooled[g * 8 + c], out2[(size_t)i * 8 + c]);
}

__global__ void finK(const float* __restrict__ pooled, const float* __restrict__ cnt,
                     const float* __restrict__ fcW, const float* __restrict__ fcb,
                     float* __restrict__ out, int G){
  int g = threadIdx.x;
  if (g >= G) return;
  float cc = fmaxf(cnt[g], 1.0f);
  float y = fcb[0];
  #pragma unroll
  for (int c = 0; c < 8; ++c) y += (pooled[g * 8 + c] / cc) * fcW[c];
  out[g] = 2.f / (1.f + expf(-y)) - 1.f;
}

extern "C" void kernel_launch(void* const* d_in, const int* in_sizes, int n_in,
                              void* d_out, int out_size, void* d_ws, size_t ws_size,
                              hipStream_t stream){
  const float* x    = (const float*)d_in[0];
  const int*   ei   = (const int*)d_in[1];
  const int*   batch= (const int*)d_in[2];
  const float* W1   = (const float*)d_in[3];
  const float* aS1  = (const float*)d_in[4];
  const float* aD1  = (const float*)d_in[5];
  const float* b1   = (const float*)d_in[6];
  const float* W2   = (const float*)d_in[7];
  const float* aS2  = (const float*)d_in[8];
  const float* aD2  = (const float*)d_in[9];
  const float* b2   = (const float*)d_in[10];
  const float* fcW  = (const float*)d_in[11];
  const float* fcb  = (const float*)d_in[12];
  float* out = (float*)d_out;

  const int N  = in_sizes[0] / 128;
  const int E  = in_sizes[1] / 2;
  const int ET = E + N;
  const int G  = 64;

  const int* eiSrc = ei;
  const int* eiDst = ei + E;

  char* w = (char*)d_ws;
  size_t o = 0;
  auto alloc = [&](size_t bytes)->char*{
    o = (o + 255) & ~(size_t)255;
    char* p = w + o;
    o += bytes;
    return p;
  };
  // zero-region (contiguous): deg, cursor, pooled, cnt
  int*   deg    = (int*)  alloc((size_t)N * 4);
  int*   cur    = (int*)  alloc((size_t)N * 4);
  float* pooled = (float*)alloc((size_t)G * 8 * 4);
  float* cnt    = (float*)alloc((size_t)G * 4);
  size_t zbytes = (size_t)((char*)(cnt + G) - (char*)deg);
  int*   csrOff = (int*)  alloc((size_t)(N + 1) * 4);
  int*   part   = (int*)  alloc(256 * 4);
  int*   csrc   = (int*)  alloc((size_t)ET * 4);
  float* elogw  = (float*)alloc((size_t)ET * 2 * 4);
  float* h1     = (float*)alloc((size_t)N * 128 * 4);
  float* a1s    = (float*)alloc((size_t)N * 2 * 4);
  float* a1d    = (float*)alloc((size_t)N * 2 * 4);
  float* out1   = (float*)alloc((size_t)N * 128 * 4);
  float* h2     = (float*)alloc((size_t)N * 8 * 4);
  float* a2s    = (float*)alloc((size_t)N * 4);
  float* a2d    = (float*)alloc((size_t)N * 4);
  float* out2   = (float*)alloc((size_t)N * 8 * 4);
  (void)ws_size; (void)n_in; (void)out_size;

  hipMemsetAsync(deg, 0, zbytes, stream);

  int ebl = (ET + 255) / 256;
  int nbl = (N + 255) / 256;   // 196 for N=50000

  countK  <<<ebl, 256, 0, stream>>>(eiDst, E, ET, deg);
  scanA   <<<nbl, 256, 0, stream>>>(deg, csrOff, part, N);
  scanB   <<<1,   256, 0, stream>>>(part, nbl);
  scanC   <<<nbl, 256, 0, stream>>>(csrOff, part, N, ET);
  scatterK<<<ebl, 256, 0, stream>>>(eiSrc, eiDst, E, ET, csrOff, cur, csrc);

  dim3 g1((N + 15) / 16, 2);
  gemm1<<<g1, 256, 0, stream>>>(x, W1, aS1, aD1, h1, a1s, a1d, N);
  agg1 <<<N, 128, 0, stream>>>(csrOff, csrc, a1s, a1d, h1, elogw, b1, out1);
  gemm2<<<(N + 31) / 32, 256, 0, stream>>>(out1, W2, aS2, aD2, h2, a2s, a2d, N);
  agg2 <<<N, 64, 0, stream>>>(csrOff, csrc, a2s, a2d, h2, elogw, b2, out2);
  poolK<<<nbl, 256, 0, stream>>>(out2, batch, pooled, cnt, N);
  finK <<<1, 64, 0, stream>>>(pooled, cnt, fcW, fcb, out, G);
}

// Round 2
// 511.137 us; speedup vs baseline: 1.8835x; 1.8835x over previous
//
#include <hip/hip_runtime.h>
#include <math.h>

__device__ __forceinline__ float lrelu(float v){ return v >= 0.f ? v : 0.2f * v; }

// ---------------- CSR build ----------------
__global__ void countK(const int* __restrict__ dstA, int E, int ET, int* __restrict__ deg){
  int e = blockIdx.x * blockDim.x + threadIdx.x;
  if (e >= ET) return;
  int d = (e < E) ? dstA[e] : (e - E);
  atomicAdd(&deg[d], 1);
}

__global__ void scanA(const int* __restrict__ deg, int* __restrict__ excl,
                      int* __restrict__ part, int n){
  __shared__ int s[256];
  int t = threadIdx.x;
  int i = blockIdx.x * 256 + t;
  int v = (i < n) ? deg[i] : 0;
  s[t] = v;
  __syncthreads();
  for (int o = 1; o < 256; o <<= 1){
    int tv = (t >= o) ? s[t - o] : 0;
    __syncthreads();
    s[t] += tv;
    __syncthreads();
  }
  if (i < n) excl[i] = s[t] - v;
  if (t == 255) part[blockIdx.x] = s[t];
}

__global__ void scanB(int* __restrict__ part, int nb){
  __shared__ int s[256];
  int t = threadIdx.x;
  int v = (t < nb) ? part[t] : 0;
  s[t] = v;
  __syncthreads();
  for (int o = 1; o < 256; o <<= 1){
    int tv = (t >= o) ? s[t - o] : 0;
    __syncthreads();
    s[t] += tv;
    __syncthreads();
  }
  if (t < nb) part[t] = s[t] - v;
}

__global__ void scanC(int* __restrict__ off, const int* __restrict__ part, int n, int ET){
  int i = blockIdx.x * 256 + threadIdx.x;
  if (i < n) off[i] += part[blockIdx.x];
  if (i == 0) off[n] = ET;
}

__global__ void scatterK(const int* __restrict__ srcA, const int* __restrict__ dstA, int E, int ET,
                         const int* __restrict__ off, int* __restrict__ cur, int* __restrict__ csrc){
  int e = blockIdx.x * blockDim.x + threadIdx.x;
  if (e >= ET) return;
  int s, d;
  if (e < E){ s = srcA[e]; d = dstA[e]; } else { s = e - E; d = s; }
  int p = off[d] + atomicAdd(&cur[d], 1);
  csrc[p] = s;
}

// ---------------- Layer 1: h1 = x@W1 fused with a_src/a_dst ----------------
__global__ __launch_bounds__(256) void gemm1(const float* __restrict__ x, const float* __restrict__ W1,
    const float* __restrict__ attS, const float* __restrict__ attD,
    float* __restrict__ h1, float* __restrict__ a1s, float* __restrict__ a1d, int nN){
  __shared__ float Ws[128][64];          // W1 columns [64*half, 64*half+64)
  int t = threadIdx.x;
  int half = blockIdx.y;                 // channel half == head (HID=64)
  for (int idx = t; idx < 128 * 64; idx += 256){
    int k = idx >> 6, c = idx & 63;
    Ws[k][c] = W1[k * 128 + half * 64 + c];
  }
  __syncthreads();
  int cl = t & 63;       // channel within head
  int slot = t >> 6;     // wave id: each wave = one node at a time, all 64 ch of this head
  float aS = attS[half * 64 + cl];
  float aD = attD[half * 64 + cl];
  int node0 = blockIdx.x * 16;
  for (int i = 0; i < 4; ++i){
    int n = node0 + slot * 4 + i;
    if (n >= nN) break;
    const float4* xr = reinterpret_cast<const float4*>(x + (size_t)n * 128);
    float acc = 0.f;
    #pragma unroll
    for (int k4 = 0; k4 < 32; ++k4){
      float4 xv = xr[k4];                       // wave-uniform broadcast
      acc = fmaf(xv.x, Ws[4 * k4 + 0][cl], acc);
      acc = fmaf(xv.y, Ws[4 * k4 + 1][cl], acc);
      acc = fmaf(xv.z, Ws[4 * k4 + 2][cl], acc);
      acc = fmaf(xv.w, Ws[4 * k4 + 3][cl], acc);
    }
    h1[(size_t)n * 128 + half * 64 + cl] = acc;
    float ps = acc * aS, pd = acc * aD;
    for (int o = 32; o > 0; o >>= 1){
      ps += __shfl_down(ps, o);
      pd += __shfl_down(pd, o);
    }
    if (cl == 0){
      a1s[n * 2 + half] = ps;
      a1d[n * 2 + half] = pd;
    }
  }
}

// ---------------- Layer 1 attention aggregation (per dst node) ----------------
__global__ __launch_bounds__(128) void agg1(const int* __restrict__ off, const int* __restrict__ csrc,
    const float* __restrict__ a1s, const float* __restrict__ a1d,
    const float* __restrict__ h1, float* __restrict__ elogw,
    const float* __restrict__ b1, float* __restrict__ out1){
  __shared__ float sred[2][2];
  int n = blockIdx.x, t = threadIdx.x;
  int start = off[n], end = off[n + 1];
  float ad0 = a1d[2 * n], ad1 = a1d[2 * n + 1];
  // pass 1: logits + max
  float lm0 = -INFINITY, lm1 = -INFINITY;
  for (int p = start + t; p < end; p += 128){
    int s = csrc[p];
    float l0 = lrelu(a1s[2 * s] + ad0);
    float l1 = lrelu(a1s[2 * s + 1] + ad1);
    elogw[2 * p] = l0; elogw[2 * p + 1] = l1;
    lm0 = fmaxf(lm0, l0); lm1 = fmaxf(lm1, l1);
  }
  for (int o = 32; o > 0; o >>= 1){
    lm0 = fmaxf(lm0, __shfl_down(lm0, o));
    lm1 = fmaxf(lm1, __shfl_down(lm1, o));
  }
  int wid = t >> 6, lane = t & 63;
  if (lane == 0){ sred[wid][0] = lm0; sred[wid][1] = lm1; }
  __syncthreads();
  float m0 = fmaxf(sred[0][0], sred[1][0]);
  float m1 = fmaxf(sred[0][1], sred[1][1]);
  __syncthreads();
  // pass 2: exp + sum
  float ls0 = 0.f, ls1 = 0.f;
  for (int p = start + t; p < end; p += 128){
    float e0 = expf(elogw[2 * p] - m0);
    float e1 = expf(elogw[2 * p + 1] - m1);
    elogw[2 * p] = e0; elogw[2 * p + 1] = e1;
    ls0 += e0; ls1 += e1;
  }
  for (int o = 32; o > 0; o >>= 1){
    ls0 += __shfl_down(ls0, o);
    ls1 += __shfl_down(ls1, o);
  }
  if (lane == 0){ sred[wid][0] = ls0; sred[wid][1] = ls1; }
  __syncthreads();
  float d0 = sred[0][0] + sred[1][0];
  float d1 = sred[0][1] + sred[1][1];
  // pass 3: weighted gather, thread t = channel
  int c = t, h = t >> 6;
  float inv = 1.f / (h ? d1 : d0);
  float bc = b1[c];
  float acc = 0.f;
  for (int p = start; p < end; ++p){
    int s = csrc[p];                               // broadcast
    acc = fmaf(elogw[2 * p + h], h1[(size_t)s * 128 + c], acc);  // coalesced 512B row
  }
  out1[(size_t)n * 128 + c] = fmaxf(fmaf(acc, inv, bc), 0.f);    // + bias, ReLU fused
}

// ---------------- Layer 2: h2 = relu(out1)@W2 fused with a_src2/a_dst2 ----------------
__global__ __launch_bounds__(256) void gemm2(const float* __restrict__ out1, const float* __restrict__ W2,
    const float* __restrict__ attS2, const float* __restrict__ attD2,
    float* __restrict__ h2, float* __restrict__ a2s, float* __restrict__ a2d, int nN){
  __shared__ float Ws[128][8];
  int t = threadIdx.x;
  for (int idx = t; idx < 1024; idx += 256) Ws[idx >> 3][idx & 7] = W2[idx];
  __syncthreads();
  int c = t & 7, nl = t >> 3;
  int n = blockIdx.x * 32 + nl;
  if (n >= nN) return;
  const float4* xr = reinterpret_cast<const float4*>(out1 + (size_t)n * 128);
  float acc = 0.f;
  #pragma unroll
  for (int k4 = 0; k4 < 32; ++k4){
    float4 xv = xr[k4];
    acc = fmaf(xv.x, Ws[4 * k4 + 0][c], acc);
    acc = fmaf(xv.y, Ws[4 * k4 + 1][c], acc);
    acc = fmaf(xv.z, Ws[4 * k4 + 2][c], acc);
    acc = fmaf(xv.w, Ws[4 * k4 + 3][c], acc);
  }
  h2[(size_t)n * 8 + c] = acc;
  float ps = acc * attS2[c], pd = acc * attD2[c];
  ps += __shfl_xor(ps, 1); ps += __shfl_xor(ps, 2); ps += __shfl_xor(ps, 4);
  pd += __shfl_xor(pd, 1); pd += __shfl_xor(pd, 2); pd += __shfl_xor(pd, 4);
  if (c == 0){ a2s[n] = ps; a2d[n] = pd; }
}

// ---------------- Layer 2 attention aggregation (one wave per node) ----------------
__global__ __launch_bounds__(64) void agg2(const int* __restrict__ off, const int* __restrict__ csrc,
    const float* __restrict__ a2s, const float* __restrict__ a2d,
    const float* __restrict__ h2, float* __restrict__ elogw,
    const float* __restrict__ b2, float* __restrict__ out2){
  int n = blockIdx.x, t = threadIdx.x;
  int start = off[n], end = off[n + 1];
  float ad = a2d[n];
  float lm = -INFINITY;
  for (int p = start + t; p < end; p += 64){
    float l = lrelu(a2s[csrc[p]] + ad);
    elogw[p] = l;
    lm = fmaxf(lm, l);
  }
  for (int o = 32; o > 0; o >>= 1) lm = fmaxf(lm, __shfl_down(lm, o));
  lm = __shfl(lm, 0);
  float ls = 0.f;
  for (int p = start + t; p < end; p += 64){
    float e = expf(elogw[p] - lm);
    elogw[p] = e;
    ls += e;
  }
  for (int o = 32; o > 0; o >>= 1) ls += __shfl_down(ls, o);
  float dv = __shfl(ls, 0);
  __syncthreads();   // make other lanes' elogw writes visible
  int c = t & 7, sub = t >> 3;
  float acc = 0.f;
  for (int p = start + sub; p < end; p += 8){
    acc = fmaf(elogw[p], h2[(size_t)csrc[p] * 8 + c], acc);
  }
  acc += __shfl_xor(acc, 8);
  acc += __shfl_xor(acc, 16);
  acc += __shfl_xor(acc, 32);
  if (t < 8) out2[(size_t)n * 8 + t] = fmaxf(acc / dv + b2[t], 0.f);
}

// ---------------- graph segment boundaries (batch is sorted) ----------------
__global__ void gsegK(const int* __restrict__ batch, int nN, int G, int* __restrict__ gstart){
  int g = blockIdx.x * blockDim.x + threadIdx.x;
  if (g > G) return;
  // first index i with batch[i] >= g
  int lo = 0, hi = nN;
  while (lo < hi){
    int mid = (lo + hi) >> 1;
    if (batch[mid] < g) lo = mid + 1; else hi = mid;
  }
  gstart[g] = lo;
}

// ---------------- fused mean-pool + FC + sigmoid (no atomics) ----------------
__global__ __launch_bounds__(256) void poolFC(const float* __restrict__ out2,
    const int* __restrict__ gstart, const float* __restrict__ fcW,
    const float* __restrict__ fcb, float* __restrict__ out){
  __shared__ float red[256];
  int g = blockIdx.x;
  int s = gstart[g], e = gstart[g + 1];
  int t = threadIdx.x;
  int c = t & 7, row = t >> 3;          // 32 rows x 8 channels
  float acc = 0.f;
  for (int i = s + row; i < e; i += 32) acc += out2[(size_t)i * 8 + c];
  red[t] = acc;
  __syncthreads();
  for (int o = 128; o >= 8; o >>= 1){
    if (t < o) red[t] += red[t + o];
    __syncthreads();
  }
  if (t == 0){
    float cc = fmaxf((float)(e - s), 1.0f);
    float y = fcb[0];
    #pragma unroll
    for (int c2 = 0; c2 < 8; ++c2) y += (red[c2] / cc) * fcW[c2];
    out[g] = 2.f / (1.f + expf(-y)) - 1.f;
  }
}

extern "C" void kernel_launch(void* const* d_in, const int* in_sizes, int n_in,
                              void* d_out, int out_size, void* d_ws, size_t ws_size,
                              hipStream_t stream){
  const float* x    = (const float*)d_in[0];
  const int*   ei   = (const int*)d_in[1];
  const int*   batch= (const int*)d_in[2];
  const float* W1   = (const float*)d_in[3];
  const float* aS1  = (const float*)d_in[4];
  const float* aD1  = (const float*)d_in[5];
  const float* b1   = (const float*)d_in[6];
  const float* W2   = (const float*)d_in[7];
  const float* aS2  = (const float*)d_in[8];
  const float* aD2  = (const float*)d_in[9];
  const float* b2   = (const float*)d_in[10];
  const float* fcW  = (const float*)d_in[11];
  const float* fcb  = (const float*)d_in[12];
  float* out = (float*)d_out;

  const int N  = in_sizes[0] / 128;
  const int E  = in_sizes[1] / 2;
  const int ET = E + N;
  const int G  = 64;

  const int* eiSrc = ei;
  const int* eiDst = ei + E;

  char* w = (char*)d_ws;
  size_t o = 0;
  auto alloc = [&](size_t bytes)->char*{
    o = (o + 255) & ~(size_t)255;
    char* p = w + o;
    o += bytes;
    return p;
  };
  // zero-region (contiguous): deg, cursor
  int*   deg    = (int*)  alloc((size_t)N * 4);
  int*   cur    = (int*)  alloc((size_t)N * 4);
  size_t zbytes = (size_t)((char*)(cur + N) - (char*)deg);
  int*   csrOff = (int*)  alloc((size_t)(N + 1) * 4);
  int*   part   = (int*)  alloc(256 * 4);
  int*   gstart = (int*)  alloc((size_t)(G + 1) * 4);
  int*   csrc   = (int*)  alloc((size_t)ET * 4);
  float* elogw  = (float*)alloc((size_t)ET * 2 * 4);
  float* h1     = (float*)alloc((size_t)N * 128 * 4);
  float* a1s    = (float*)alloc((size_t)N * 2 * 4);
  float* a1d    = (float*)alloc((size_t)N * 2 * 4);
  float* out1   = (float*)alloc((size_t)N * 128 * 4);
  float* h2     = (float*)alloc((size_t)N * 8 * 4);
  float* a2s    = (float*)alloc((size_t)N * 4);
  float* a2d    = (float*)alloc((size_t)N * 4);
  float* out2   = (float*)alloc((size_t)N * 8 * 4);
  (void)ws_size; (void)n_in; (void)out_size;

  hipMemsetAsync(deg, 0, zbytes, stream);

  int ebl = (ET + 255) / 256;
  int nbl = (N + 255) / 256;   // 196 for N=50000

  countK  <<<ebl, 256, 0, stream>>>(eiDst, E, ET, deg);
  scanA   <<<nbl, 256, 0, stream>>>(deg, csrOff, part, N);
  scanB   <<<1,   256, 0, stream>>>(part, nbl);
  scanC   <<<nbl, 256, 0, stream>>>(csrOff, part, N, ET);
  scatterK<<<ebl, 256, 0, stream>>>(eiSrc, eiDst, E, ET, csrOff, cur, csrc);
  gsegK   <<<1, 128, 0, stream>>>(batch, N, G, gstart);

  dim3 g1((N + 15) / 16, 2);
  gemm1<<<g1, 256, 0, stream>>>(x, W1, aS1, aD1, h1, a1s, a1d, N);
  agg1 <<<N, 128, 0, stream>>>(csrOff, csrc, a1s, a1d, h1, elogw, b1, out1);
  gemm2<<<(N + 31) / 32, 256, 0, stream>>>(out1, W2, aS2, aD2, h2, a2s, a2d, N);
  agg2 <<<N, 64, 0, stream>>>(csrOff, csrc, a2s, a2d, h2, elogw, b2, out2);
  poolFC<<<G, 256, 0, stream>>>(out2, gstart, fcW, fcb, out);
}